// Round 4
// baseline (375.329 us; speedup 1.0000x reference)
//
#include <hip/hip_runtime.h>

#define N_ 16384
#define D_ 256
#define LOG2E 1.4426950408889634f

typedef __attribute__((ext_vector_type(8))) short short8;
typedef __attribute__((ext_vector_type(4))) float floatx4;

typedef __attribute__((address_space(1))) const unsigned int gu32_t;
typedef __attribute__((address_space(3))) unsigned int lu32_t;

__device__ __forceinline__ void async16(const void* g, void* l) {
  __builtin_amdgcn_global_load_lds((gu32_t*)g, (lu32_t*)l, 16, 0, 0);
}

__device__ __forceinline__ unsigned short f2bf(float x) {
  unsigned int u = __float_as_uint(x);
  u += 0x7fffu + ((u >> 16) & 1u);
  return (unsigned short)(u >> 16);
}

// ---------------- prep: fp32 -> bf16, packed in MFMA-fragment order ----------------
// PA/PB layout: 16B unit at index ((R*8+kc)*4+q)*16 + m  holds  X[R*16+m][kc*32+q*8 .. +8)
// so a 16x16x32 fragment for (R,kc) is one contiguous 1024B block, lane-contiguous.
__global__ void prep_pack(const float* __restrict__ img, const float* __restrict__ txt,
                          const float* __restrict__ ls, short* __restrict__ PA,
                          short* __restrict__ PB, float* __restrict__ accv) {
  int idx = blockIdx.x * 256 + threadIdx.x;  // 0 .. N*D/8-1 (524288)
  int m = idx & 15, q = (idx >> 4) & 3, kc = (idx >> 6) & 7, R = idx >> 9;
  int row = R * 16 + m, k0 = kc * 32 + q * 8;
  float s2 = ls[0] * LOG2E;
  const float4* sa = (const float4*)(img + (size_t)row * D_ + k0);
  const float4* sb = (const float4*)(txt + (size_t)row * D_ + k0);
  float4 a0 = sa[0], a1 = sa[1];
  float4 b0 = sb[0], b1 = sb[1];
  short8 oa, ob;
  oa[0] = (short)f2bf(a0.x * s2); oa[1] = (short)f2bf(a0.y * s2);
  oa[2] = (short)f2bf(a0.z * s2); oa[3] = (short)f2bf(a0.w * s2);
  oa[4] = (short)f2bf(a1.x * s2); oa[5] = (short)f2bf(a1.y * s2);
  oa[6] = (short)f2bf(a1.z * s2); oa[7] = (short)f2bf(a1.w * s2);
  ob[0] = (short)f2bf(b0.x); ob[1] = (short)f2bf(b0.y);
  ob[2] = (short)f2bf(b0.z); ob[3] = (short)f2bf(b0.w);
  ob[4] = (short)f2bf(b1.x); ob[5] = (short)f2bf(b1.y);
  ob[6] = (short)f2bf(b1.z); ob[7] = (short)f2bf(b1.w);
  ((short8*)PA)[idx] = oa;
  ((short8*)PB)[idx] = ob;
  if (idx == 0) accv[0] = 0.0f;
}

// ---------------- diag: exact fp32 diagonal in log2 domain ----------------
__global__ void diag_kernel(const float* __restrict__ img, const float* __restrict__ txt,
                            const float* __restrict__ ls, float* __restrict__ diag2) {
  int row = blockIdx.x * 4 + (threadIdx.x >> 6);
  int lane = threadIdx.x & 63;
  float4 a = ((const float4*)(img + (size_t)row * D_))[lane];
  float4 b = ((const float4*)(txt + (size_t)row * D_))[lane];
  float s = a.x * b.x + a.y * b.y + a.z * b.z + a.w * b.w;
  #pragma unroll
  for (int off = 1; off < 64; off <<= 1) s += __shfl_xor(s, off);
  if (lane == 0) diag2[row] = s * ls[0] * LOG2E;
}

// ---------------- persistent stripe-sweep gemm + stats ----------------
// 256 blocks (128 row-stripes x 2 col-halves), 512 threads = 8 waves (4 wrow x 2 wcol).
// A: 64 rows-group? wave owns 32 rows x K=256 in registers (16 x short8).
// B: streamed, double-buffered LDS 2x32KB, global_load_lds 16B, 1 barrier/chunk.
// j-loop: 32 tiles of 256 cols; per tile 4 chunks (K=64 each) -> 32 MFMAs/chunk/wave.
__global__ __launch_bounds__(512, 2)
void gemm_stats(const short* __restrict__ PA, const short* __restrict__ PB,
                float2* __restrict__ pR, float2* __restrict__ pC,
                const float* __restrict__ diag2) {
  __shared__ char smem[75776];
  // [0,65536): two 32KB staging buffers; [65536,73728): colbuf float2[4][256];
  // [73728,75776): rowbuf float2[2][128]
  float2* colbuf = (float2*)(smem + 65536);
  float2* rowbuf = (float2*)(smem + 73728);

  const int tid = threadIdx.x, lane = tid & 63, wv = tid >> 6;
  const int wrow = wv >> 1, wcol = wv & 1;
  const int q = lane >> 4, c = lane & 15;
  const int stripe = blockIdx.x >> 1, half = blockIdx.x & 1;
  const int r0 = stripe * 128, c0 = half * 8192;

  // ---- A panel into registers: rows r0 + wrow*32 .. +32, all K.
  short8 areg[2][8];
  const int Rg0 = (r0 >> 4) + wrow * 2;
  #pragma unroll
  for (int rt = 0; rt < 2; ++rt)
    #pragma unroll
    for (int kc = 0; kc < 8; ++kc)
      areg[rt][kc] = *(const short8*)(PA + (size_t)((Rg0 + rt) * 8 + kc) * 512 + lane * 8);

  floatx4 acc[2][8];
  float Mr[2][4], Sr[2][4];
  #pragma unroll
  for (int rt = 0; rt < 2; ++rt)
    #pragma unroll
    for (int r = 0; r < 4; ++r) { Mr[rt][r] = -3.0e38f; Sr[rt][r] = 0.f; }

  auto issue_chunk = [&](int j, int cc, int buf) {
    int Cb = (c0 >> 4) + j * 16;
    #pragma unroll
    for (int rr = 0; rr < 4; ++rr) {
      int f = rr * 8 + wv;                  // wave-uniform
      int t = f >> 1, kcl = f & 1;
      const short* src = PB + (size_t)((Cb + t) * 8 + cc * 2 + kcl) * 512 + lane * 8;
      async16(src, smem + buf * 32768 + f * 1024);
    }
  };
  auto compute_chunk = [&](int cc, int buf) {
    char* base = smem + buf * 32768;
    #pragma unroll
    for (int kcl = 0; kcl < 2; ++kcl) {
      int kc = cc * 2 + kcl;
      short8 bf[8];
      #pragma unroll
      for (int ct = 0; ct < 8; ++ct)
        bf[ct] = *(const short8*)(base + ((wcol * 8 + ct) * 2 + kcl) * 1024 + lane * 16);
      #pragma unroll
      for (int rt = 0; rt < 2; ++rt)
        #pragma unroll
        for (int ct = 0; ct < 8; ++ct)
          acc[rt][ct] = __builtin_amdgcn_mfma_f32_16x16x32_bf16(areg[rt][kc], bf[ct],
                                                                acc[rt][ct], 0, 0, 0);
    }
  };

  issue_chunk(0, 0, 0);
  int buf = 0;

  for (int j = 0; j < 32; ++j) {
    #pragma unroll
    for (int rt = 0; rt < 2; ++rt)
      #pragma unroll
      for (int ct = 0; ct < 8; ++ct)
        acc[rt][ct] = (floatx4){0.f, 0.f, 0.f, 0.f};

    for (int cc = 0; cc < 4; ++cc) {
      asm volatile("s_waitcnt vmcnt(0)" ::: "memory");
      __syncthreads();
      if (!(j == 31 && cc == 3)) {
        int nj = (cc == 3) ? j + 1 : j;
        issue_chunk(nj, (cc + 1) & 3, buf ^ 1);
      }
      compute_chunk(cc, buf);
      buf ^= 1;
    }

    // ---- stats for this j-tile. acc[rt][ct][reg] = logit2 at
    // row = r0 + wrow*32 + rt*16 + q*4 + reg, col = c0 + j*256 + wcol*128 + ct*16 + c
    float v = acc[0][0][0];
    #pragma unroll
    for (int rt = 0; rt < 2; ++rt)
      #pragma unroll
      for (int ct = 0; ct < 8; ++ct)
        #pragma unroll
        for (int r = 0; r < 4; ++r) v = fmaxf(v, acc[rt][ct][r]);
    #pragma unroll
    for (int off = 1; off < 64; off <<= 1) v = fmaxf(v, __shfl_xor(v, off));
    float msub = v - 90.f;

    #pragma unroll
    for (int rt = 0; rt < 2; ++rt)
      #pragma unroll
      for (int ct = 0; ct < 8; ++ct)
        #pragma unroll
        for (int r = 0; r < 4; ++r)
          acc[rt][ct][r] = exp2f(acc[rt][ct][r] - msub);

    // row partials: sum over ct + 16-lane (c) butterfly, then online register merge
    #pragma unroll
    for (int rt = 0; rt < 2; ++rt)
      #pragma unroll
      for (int r = 0; r < 4; ++r) {
        float rp = acc[rt][0][r];
        #pragma unroll
        for (int ct = 1; ct < 8; ++ct) rp += acc[rt][ct][r];
        #pragma unroll
        for (int off = 1; off < 16; off <<= 1) rp += __shfl_xor(rp, off);
        float Mo = Mr[rt][r];
        float nM = fmaxf(Mo, msub);
        float nS = Sr[rt][r] * exp2f(Mo - nM) + rp * exp2f(msub - nM);
        bool upd = rp > 0.f;
        Mr[rt][r] = upd ? nM : Mo;
        Sr[rt][r] = upd ? nS : Sr[rt][r];
      }

    // col partials: lane-local sum over rt,reg + q butterfly (xor 16,32)
    #pragma unroll
    for (int ct = 0; ct < 8; ++ct) {
      float cp = 0.f;
      #pragma unroll
      for (int rt = 0; rt < 2; ++rt)
        #pragma unroll
        for (int r = 0; r < 4; ++r) cp += acc[rt][ct][r];
      cp += __shfl_xor(cp, 16);
      cp += __shfl_xor(cp, 32);
      if (lane < 16) colbuf[wrow * 256 + wcol * 128 + ct * 16 + c] = make_float2(msub, cp);
    }
    __syncthreads();
    if (tid < 256) {
      float M = -3.0e38f, L = 0.f;
      #pragma unroll
      for (int k = 0; k < 4; ++k) {
        float2 w = colbuf[k * 256 + tid];
        if (w.y > 0.f) {
          if (w.x > M) { L = L * exp2f(M - w.x) + w.y; M = w.x; }
          else         { L += w.y * exp2f(w.x - M); }
        }
      }
      pC[(size_t)stripe * N_ + c0 + j * 256 + tid] = make_float2(M, L);
    }
    __syncthreads();
  }

  // ---- row partials out: merge the two wcol halves
  if (c == 0) {
    #pragma unroll
    for (int rt = 0; rt < 2; ++rt)
      #pragma unroll
      for (int r = 0; r < 4; ++r)
        rowbuf[wcol * 128 + wrow * 32 + rt * 16 + q * 4 + r] = make_float2(Mr[rt][r], Sr[rt][r]);
  }
  __syncthreads();
  if (tid < 128) {
    float2 w0 = rowbuf[tid], w1 = rowbuf[128 + tid];
    float M = -3.0e38f, L = 0.f;
    if (w0.y > 0.f) { M = w0.x; L = w0.y; }
    if (w1.y > 0.f) {
      if (w1.x > M) { L = L * exp2f(M - w1.x) + w1.y; M = w1.x; }
      else          { L += w1.y * exp2f(w1.x - M); }
    }
    pR[(size_t)half * N_ + r0 + tid] = make_float2(M, L);
  }
}

// ---------------- merge: rows (2 partials) + cols (128 partials) -> LSE -> loss sum ----------------
__global__ void merge_kernel(const float2* __restrict__ pR, const float2* __restrict__ pC,
                             const float* __restrict__ diag2, float* __restrict__ accv) {
  int idx = blockIdx.x * 256 + threadIdx.x;  // 0..2N-1
  float M = -3.0e38f, L = 0.f;
  int i;
  if (idx < N_) {
    i = idx;
    float2 w0 = pR[i], w1 = pR[N_ + i];
    if (w0.y > 0.f) { M = w0.x; L = w0.y; }
    if (w1.y > 0.f) {
      if (w1.x > M) { L = L * exp2f(M - w1.x) + w1.y; M = w1.x; }
      else          { L += w1.y * exp2f(w1.x - M); }
    }
  } else {
    i = idx - N_;
    for (int s = 0; s < 128; ++s) {
      float2 w = pC[(size_t)s * N_ + i];
      if (w.y > 0.f) {
        if (w.x > M) { L = L * exp2f(M - w.x) + w.y; M = w.x; }
        else         { L += w.y * exp2f(w.x - M); }
      }
    }
  }
  float val = (M + log2f(fmaxf(L, 1e-45f))) - diag2[i];

  __shared__ float red[256];
  red[threadIdx.x] = val;
  __syncthreads();
  #pragma unroll
  for (int s = 128; s > 0; s >>= 1) {
    if (threadIdx.x < s) red[threadIdx.x] += red[threadIdx.x + s];
    __syncthreads();
  }
  if (threadIdx.x == 0) atomicAdd(accv, red[0]);
}

__global__ void finalize_kernel(const float* __restrict__ accv, float* __restrict__ out) {
  out[0] = accv[0] * (0.69314718055994531f / 32768.0f);  // ln2 / (2N)
}

// ---------------- launch ----------------
extern "C" void kernel_launch(void* const* d_in, const int* in_sizes, int n_in,
                              void* d_out, int out_size, void* d_ws, size_t ws_size,
                              hipStream_t stream) {
  const float* img = (const float*)d_in[0];
  const float* txt = (const float*)d_in[1];
  const float* ls  = (const float*)d_in[2];
  float* out = (float*)d_out;

  char* ws = (char*)d_ws;
  short* PA    = (short*)(ws);                 //  8 MB
  short* PB    = (short*)(ws + 8388608);       //  8 MB
  float* diag2 = (float*)(ws + 16777216);      //  64 KB
  float* accv  = (float*)(ws + 16842752);      //  256 B
  float2* pR   = (float2*)(ws + 16843008);     //  256 KB (2 x N)
  float2* pC   = (float2*)(ws + 17105152);     //  16 MB (128 x N)

  hipLaunchKernelGGL(prep_pack, dim3(2048), dim3(256), 0, stream, img, txt, ls, PA, PB, accv);
  hipLaunchKernelGGL(diag_kernel, dim3(N_ / 4), dim3(256), 0, stream, img, txt, ls, diag2);
  hipLaunchKernelGGL(gemm_stats, dim3(256), dim3(512), 0, stream, PA, PB, pR, pC, diag2);
  hipLaunchKernelGGL(merge_kernel, dim3(2 * N_ / 256), dim3(256), 0, stream, pR, pC, diag2, accv);
  hipLaunchKernelGGL(finalize_kernel, dim3(1), dim3(1), 0, stream, accv, out);
}

// Round 5
// 343.897 us; speedup vs baseline: 1.0914x; 1.0914x over previous
//
#include <hip/hip_runtime.h>

#define N_ 16384
#define D_ 256
#define LOG2E 1.4426950408889634f

typedef __attribute__((ext_vector_type(8))) short short8;
typedef __attribute__((ext_vector_type(16))) float floatx16;

typedef __attribute__((address_space(1))) const unsigned int gu32_t;
typedef __attribute__((address_space(3))) unsigned int lu32_t;

__device__ __forceinline__ void async16(const void* g, void* l) {
  __builtin_amdgcn_global_load_lds((gu32_t*)g, (lu32_t*)l, 16, 0, 0);
}

__device__ __forceinline__ unsigned short f2bf(float x) {
  unsigned int u = __float_as_uint(x);
  u += 0x7fffu + ((u >> 16) & 1u);
  return (unsigned short)(u >> 16);
}

// ---------------- prep: fp32 -> bf16, packed in 32x32x16-fragment order ----------------
// Unit (16B) uidx = (G*16+ks)*64 + h*32 + m  holds  X[G*32+m][ks*16+h*8 .. +8)
// -> the A/B fragment for (group G, k-step ks) is one contiguous 1024B block,
//    ordered exactly lane-contiguous (lane = h*32+m) for mfma_32x32x16.
__global__ void prep_pack(const float* __restrict__ img, const float* __restrict__ txt,
                          const float* __restrict__ ls, short* __restrict__ PA,
                          short* __restrict__ PB, float* __restrict__ accv) {
  int t = blockIdx.x * 256 + threadIdx.x;  // 0 .. N*D/8-1
  int row = t >> 5, kq = t & 31;
  int G = row >> 5, m = row & 31, ks = kq >> 1, h = kq & 1;
  int uidx = (G * 16 + ks) * 64 + h * 32 + m;
  float s2 = ls[0] * LOG2E;
  const float4* sa = (const float4*)(img + (size_t)row * D_ + kq * 8);
  const float4* sb = (const float4*)(txt + (size_t)row * D_ + kq * 8);
  float4 a0 = sa[0], a1 = sa[1];
  float4 b0 = sb[0], b1 = sb[1];
  short8 oa, ob;
  oa[0] = (short)f2bf(a0.x * s2); oa[1] = (short)f2bf(a0.y * s2);
  oa[2] = (short)f2bf(a0.z * s2); oa[3] = (short)f2bf(a0.w * s2);
  oa[4] = (short)f2bf(a1.x * s2); oa[5] = (short)f2bf(a1.y * s2);
  oa[6] = (short)f2bf(a1.z * s2); oa[7] = (short)f2bf(a1.w * s2);
  ob[0] = (short)f2bf(b0.x); ob[1] = (short)f2bf(b0.y);
  ob[2] = (short)f2bf(b0.z); ob[3] = (short)f2bf(b0.w);
  ob[4] = (short)f2bf(b1.x); ob[5] = (short)f2bf(b1.y);
  ob[6] = (short)f2bf(b1.z); ob[7] = (short)f2bf(b1.w);
  ((short8*)PA)[uidx] = oa;
  ((short8*)PB)[uidx] = ob;
  if (t == 0) accv[0] = 0.0f;
}

// ---------------- diag: exact fp32 diagonal in log2 domain ----------------
__global__ void diag_kernel(const float* __restrict__ img, const float* __restrict__ txt,
                            const float* __restrict__ ls, float* __restrict__ diag2) {
  int row = blockIdx.x * 4 + (threadIdx.x >> 6);
  int lane = threadIdx.x & 63;
  float4 a = ((const float4*)(img + (size_t)row * D_))[lane];
  float4 b = ((const float4*)(txt + (size_t)row * D_))[lane];
  float s = a.x * b.x + a.y * b.y + a.z * b.z + a.w * b.w;
  #pragma unroll
  for (int off = 1; off < 64; off <<= 1) s += __shfl_xor(s, off);
  if (lane == 0) diag2[row] = s * ls[0] * LOG2E;
}

// ---------------- gemm + stats: 128x128 tiles, j-sweep of 8 per block ----------------
// Grid (16 col-groups, 128 stripes). 256 thr = 4 waves (2 wr x 2 wc), wave tile 64x64
// = 2x2 of mfma_32x32x16. A/B fragments pre-packed -> staging = linear 16B DMA,
// fragment reads lane-contiguous (conflict-free). Row LSE state lives in owner-thread
// registers across the 8-tile sweep; per-tile shared wave max (-90) + zero-skip merges.
__global__ __launch_bounds__(256, 4)
void gemm_stats(const short* __restrict__ PA, const short* __restrict__ PB,
                float2* __restrict__ pR, float2* __restrict__ pC) {
  __shared__ __align__(16) char smem[35856];
  // staging: As [0,16384), Bs [16384,32768)
  // stats (aliases staging, barrier-separated): rowbuf f32[64 slots][132] @0 (33792 B)
  // colbuf float2[2][128] @33792 (2048 B); wmaxb f32[4] @35840
  float* rowbuf  = (float*)smem;
  float2* colbuf = (float2*)(smem + 33792);
  float* wmaxb   = (float*)(smem + 35840);

  const int tid = threadIdx.x, lane = tid & 63, wv = tid >> 6;
  const int wr = wv >> 1, wc = wv & 1;
  const int m = lane & 31, h = lane >> 5;
  const int bx = blockIdx.x, by = blockIdx.y;
  const int r0 = by * 128;

  // A staging source for this block's wave (group Ga0+wv), unit-contiguous
  const short* srcA = PA + ((size_t)(by * 4 + wv) * 16) * 512 + lane * 8;

  float Mr = -3.0e38f, Sr = 0.f;  // row LSE state (owner threads: tid even)
  const int R = tid >> 1, half = tid & 1;

  floatx16 acc[2][2];

  for (int j = 0; j < 8; ++j) {
    #pragma unroll
    for (int rt = 0; rt < 2; ++rt)
      #pragma unroll
      for (int nt = 0; nt < 2; ++nt)
        #pragma unroll
        for (int r = 0; r < 16; ++r) acc[rt][nt][r] = 0.f;

    const short* srcB = PB + ((size_t)(bx * 32 + j * 4 + wv) * 16) * 512 + lane * 8;

    for (int kc = 0; kc < 4; ++kc) {
      #pragma unroll
      for (int i = 0; i < 4; ++i) {
        async16(srcA + (size_t)(kc * 4 + i) * 512, smem + (wv * 4 + i) * 1024);
        async16(srcB + (size_t)(kc * 4 + i) * 512, smem + 16384 + (wv * 4 + i) * 1024);
      }
      asm volatile("s_waitcnt vmcnt(0)" ::: "memory");
      __syncthreads();
      #pragma unroll
      for (int ks = 0; ks < 4; ++ks) {
        short8 a0 = *(const short8*)(smem + ((wr * 2 + 0) * 4 + ks) * 1024 + lane * 16);
        short8 a1 = *(const short8*)(smem + ((wr * 2 + 1) * 4 + ks) * 1024 + lane * 16);
        short8 b0 = *(const short8*)(smem + 16384 + ((wc * 2 + 0) * 4 + ks) * 1024 + lane * 16);
        short8 b1 = *(const short8*)(smem + 16384 + ((wc * 2 + 1) * 4 + ks) * 1024 + lane * 16);
        acc[0][0] = __builtin_amdgcn_mfma_f32_32x32x16_bf16(a0, b0, acc[0][0], 0, 0, 0);
        acc[0][1] = __builtin_amdgcn_mfma_f32_32x32x16_bf16(a0, b1, acc[0][1], 0, 0, 0);
        acc[1][0] = __builtin_amdgcn_mfma_f32_32x32x16_bf16(a1, b0, acc[1][0], 0, 0, 0);
        acc[1][1] = __builtin_amdgcn_mfma_f32_32x32x16_bf16(a1, b1, acc[1][1], 0, 0, 0);
      }
      __syncthreads();
    }

    // ---- stats. acc[rt][nt][reg]: row = wr*64+rt*32+(reg&3)+8*(reg>>2)+4*h,
    //                               col = wc*64+nt*32+m   (within 128x128 tile)
    float v = -3.0e38f;
    #pragma unroll
    for (int rt = 0; rt < 2; ++rt)
      #pragma unroll
      for (int nt = 0; nt < 2; ++nt)
        #pragma unroll
        for (int r = 0; r < 16; ++r) v = fmaxf(v, acc[rt][nt][r]);
    #pragma unroll
    for (int off = 1; off < 64; off <<= 1) v = fmaxf(v, __shfl_xor(v, off));
    float msub = v - 90.f;
    if (lane == 0) wmaxb[wv] = msub;

    #pragma unroll
    for (int rt = 0; rt < 2; ++rt)
      #pragma unroll
      for (int nt = 0; nt < 2; ++nt)
        #pragma unroll
        for (int r = 0; r < 16; ++r) acc[rt][nt][r] = exp2f(acc[rt][nt][r] - msub);

    // col partials (sum over 64 rows of the wave tile)
    #pragma unroll
    for (int nt = 0; nt < 2; ++nt) {
      float cp = 0.f;
      #pragma unroll
      for (int r = 0; r < 16; ++r) cp += acc[0][nt][r] + acc[1][nt][r];
      cp += __shfl_xor(cp, 32);
      if (h == 0) colbuf[wr * 128 + wc * 64 + nt * 32 + m] = make_float2(msub, cp);
    }

    // row partials: nt-add, pack 4 consecutive rows -> b128 scatter rowbuf[slot][row]
    #pragma unroll
    for (int rt = 0; rt < 2; ++rt)
      #pragma unroll
      for (int rq = 0; rq < 4; ++rq) {
        float4 rp;
        rp.x = acc[rt][0][rq * 4 + 0] + acc[rt][1][rq * 4 + 0];
        rp.y = acc[rt][0][rq * 4 + 1] + acc[rt][1][rq * 4 + 1];
        rp.z = acc[rt][0][rq * 4 + 2] + acc[rt][1][rq * 4 + 2];
        rp.w = acc[rt][0][rq * 4 + 3] + acc[rt][1][rq * 4 + 3];
        int slot = wc * 32 + m;
        int rowb = wr * 64 + rt * 32 + rq * 8 + h * 4;
        *(float4*)&rowbuf[slot * 132 + rowb] = rp;
      }
    __syncthreads();

    // col merge (2 wr partials) -> pC
    if (tid < 128) {
      float2 c0 = colbuf[tid], c1 = colbuf[128 + tid];
      float M = -3.0e38f, L = 0.f;
      if (c0.y > 0.f) { M = c0.x; L = c0.y; }
      if (c1.y > 0.f) {
        if (c1.x > M) { L = L * exp2f(M - c1.x) + c1.y; M = c1.x; }
        else          { L += c1.y * exp2f(c1.x - M); }
      }
      pC[(size_t)by * N_ + bx * 1024 + j * 128 + tid] = make_float2(M, L);
    }

    // row owners: 2 threads/row sum 32 slots each, pair-merge, online update
    {
      float s = 0.f;
      #pragma unroll
      for (int k = 0; k < 32; ++k) s += rowbuf[(half * 32 + k) * 132 + R];
      float mh = wmaxb[(R >> 6) * 2 + half];
      float so = __shfl_xor(s, 1);
      float mo = __shfl_xor(mh, 1);
      if (s > 0.f) {
        if (mh > Mr) { Sr = Sr * exp2f(Mr - mh) + s; Mr = mh; }
        else         { Sr += s * exp2f(mh - Mr); }
      }
      if (so > 0.f) {
        if (mo > Mr) { Sr = Sr * exp2f(Mr - mo) + so; Mr = mo; }
        else         { Sr += so * exp2f(mo - Mr); }
      }
    }
    __syncthreads();
  }

  if (half == 0) pR[(size_t)bx * N_ + r0 + R] = make_float2(Mr, Sr);
}

// ---------------- merge: rows (16 partials) + cols (128 partials) -> LSE -> loss ----------------
__global__ void merge_kernel(const float2* __restrict__ pR, const float2* __restrict__ pC,
                             const float* __restrict__ diag2, float* __restrict__ accv) {
  int idx = blockIdx.x * 256 + threadIdx.x;  // 0..2N-1
  float M = -3.0e38f, L = 0.f;
  int i;
  if (idx < N_) {
    i = idx;
    #pragma unroll
    for (int g = 0; g < 16; ++g) {
      float2 w = pR[(size_t)g * N_ + i];
      if (w.y > 0.f) {
        if (w.x > M) { L = L * exp2f(M - w.x) + w.y; M = w.x; }
        else         { L += w.y * exp2f(w.x - M); }
      }
    }
  } else {
    i = idx - N_;
    for (int s = 0; s < 128; ++s) {
      float2 w = pC[(size_t)s * N_ + i];
      if (w.y > 0.f) {
        if (w.x > M) { L = L * exp2f(M - w.x) + w.y; M = w.x; }
        else         { L += w.y * exp2f(w.x - M); }
      }
    }
  }
  float val = (M + log2f(fmaxf(L, 1e-45f))) - diag2[i];

  __shared__ float red[256];
  red[threadIdx.x] = val;
  __syncthreads();
  #pragma unroll
  for (int s = 128; s > 0; s >>= 1) {
    if (threadIdx.x < s) red[threadIdx.x] += red[threadIdx.x + s];
    __syncthreads();
  }
  if (threadIdx.x == 0) atomicAdd(accv, red[0]);
}

__global__ void finalize_kernel(const float* __restrict__ accv, float* __restrict__ out) {
  out[0] = accv[0] * (0.69314718055994531f / 32768.0f);  // ln2 / (2N)
}

// ---------------- launch ----------------
extern "C" void kernel_launch(void* const* d_in, const int* in_sizes, int n_in,
                              void* d_out, int out_size, void* d_ws, size_t ws_size,
                              hipStream_t stream) {
  const float* img = (const float*)d_in[0];
  const float* txt = (const float*)d_in[1];
  const float* ls  = (const float*)d_in[2];
  float* out = (float*)d_out;

  char* ws = (char*)d_ws;
  short* PA    = (short*)(ws);                 //  8 MB
  short* PB    = (short*)(ws + 8388608);       //  8 MB
  float* diag2 = (float*)(ws + 16777216);      //  64 KB
  float* accv  = (float*)(ws + 16842752);      //  256 B
  float2* pR   = (float2*)(ws + 16843008);     //  2 MB  (16 x N)
  float2* pC   = (float2*)(ws + 18940160);     //  16 MB (128 x N)

  hipLaunchKernelGGL(prep_pack, dim3(2048), dim3(256), 0, stream, img, txt, ls, PA, PB, accv);
  hipLaunchKernelGGL(diag_kernel, dim3(N_ / 4), dim3(256), 0, stream, img, txt, ls, diag2);
  hipLaunchKernelGGL(gemm_stats, dim3(16, 128), dim3(256), 0, stream, PA, PB, pR, pC);
  hipLaunchKernelGGL(merge_kernel, dim3(2 * N_ / 256), dim3(256), 0, stream, pR, pC, diag2, accv);
  hipLaunchKernelGGL(finalize_kernel, dim3(1), dim3(1), 0, stream, accv, out);
}

// Round 6
// 281.634 us; speedup vs baseline: 1.3327x; 1.2211x over previous
//
#include <hip/hip_runtime.h>

#define N_ 16384
#define D_ 256
#define LOG2E 1.4426950408889634f
#define HEXP2(x) __builtin_amdgcn_exp2f(x)

typedef __attribute__((ext_vector_type(8))) short short8;
typedef __attribute__((ext_vector_type(16))) float floatx16;

typedef __attribute__((address_space(1))) const unsigned int gu32_t;
typedef __attribute__((address_space(3))) unsigned int lu32_t;

__device__ __forceinline__ void async16(const void* g, void* l) {
  __builtin_amdgcn_global_load_lds((gu32_t*)g, (lu32_t*)l, 16, 0, 0);
}

__device__ __forceinline__ unsigned short f2bf(float x) {
  unsigned int u = __float_as_uint(x);
  u += 0x7fffu + ((u >> 16) & 1u);
  return (unsigned short)(u >> 16);
}

// ---------------- prep: fp32 -> bf16, packed in 32x32x16-fragment order ----------------
// 16B unit uidx = (G*16+ks)*64 + h*32 + m  holds  X[G*32+m][ks*16+h*8 .. +8)
// -> fragment (G, ks) = contiguous 1024B, lane-contiguous (lane = h*32+m).
__global__ void prep_pack(const float* __restrict__ img, const float* __restrict__ txt,
                          const float* __restrict__ ls, short* __restrict__ PA,
                          short* __restrict__ PB, float* __restrict__ accv) {
  int t = blockIdx.x * 256 + threadIdx.x;  // 0 .. N*D/8-1
  int row = t >> 5, kq = t & 31;
  int G = row >> 5, m = row & 31, ks = kq >> 1, h = kq & 1;
  int uidx = (G * 16 + ks) * 64 + h * 32 + m;
  float s2 = ls[0] * LOG2E;
  const float4* sa = (const float4*)(img + (size_t)row * D_ + kq * 8);
  const float4* sb = (const float4*)(txt + (size_t)row * D_ + kq * 8);
  float4 a0 = sa[0], a1 = sa[1];
  float4 b0 = sb[0], b1 = sb[1];
  short8 oa, ob;
  oa[0] = (short)f2bf(a0.x * s2); oa[1] = (short)f2bf(a0.y * s2);
  oa[2] = (short)f2bf(a0.z * s2); oa[3] = (short)f2bf(a0.w * s2);
  oa[4] = (short)f2bf(a1.x * s2); oa[5] = (short)f2bf(a1.y * s2);
  oa[6] = (short)f2bf(a1.z * s2); oa[7] = (short)f2bf(a1.w * s2);
  ob[0] = (short)f2bf(b0.x); ob[1] = (short)f2bf(b0.y);
  ob[2] = (short)f2bf(b0.z); ob[3] = (short)f2bf(b0.w);
  ob[4] = (short)f2bf(b1.x); ob[5] = (short)f2bf(b1.y);
  ob[6] = (short)f2bf(b1.z); ob[7] = (short)f2bf(b1.w);
  ((short8*)PA)[uidx] = oa;
  ((short8*)PB)[uidx] = ob;
  if (t == 0) accv[0] = 0.0f;
}

// ---------------- diag: exact fp32 diagonal in log2 domain ----------------
__global__ void diag_kernel(const float* __restrict__ img, const float* __restrict__ txt,
                            const float* __restrict__ ls, float* __restrict__ diag2) {
  int row = blockIdx.x * 4 + (threadIdx.x >> 6);
  int lane = threadIdx.x & 63;
  float4 a = ((const float4*)(img + (size_t)row * D_))[lane];
  float4 b = ((const float4*)(txt + (size_t)row * D_))[lane];
  float s = a.x * b.x + a.y * b.y + a.z * b.z + a.w * b.w;
  #pragma unroll
  for (int off = 1; off < 64; off <<= 1) s += __shfl_xor(s, off);
  if (lane == 0) diag2[row] = s * ls[0] * LOG2E;
}

// ---------------- gemm + stats: A-in-registers, continuous B pipeline ----------------
// Grid (128 stripes [x, fast], 8 colgroups [y]). 256 thr = 4 waves (2 wr x 2 wc).
// Wave tile 64x64 = 2x2 of mfma_32x32x16; A panel (64 rows x K=256) in 128 VGPRs.
// B streamed via global_load_lds into 2x16KB LDS, 2 chunks ahead, vmcnt(4) + raw
// s_barrier (no full drains; DMA stays in flight across stats). Stats LDS separate.
__global__ __launch_bounds__(256, 2)
void gemm_stats(const short* __restrict__ PA, const short* __restrict__ PB,
                float2* __restrict__ pR, float2* __restrict__ pC) {
  __shared__ __align__(16) char smem[73728];
  // [0,32768): B staging dbuf (2 x 16KB, 16 frags x 1KB each)
  // [32768,71680): rowbuf f32 [wr*64+slot][76] (38912 B)
  // [71680,73728): colbuf float2[2][128]
  float* rowbuf  = (float*)(smem + 32768);
  float2* colbuf = (float2*)(smem + 71680);

  const int tid = threadIdx.x, lane = tid & 63, wv = tid >> 6;
  const int wr = wv >> 1, wc = wv & 1;
  const int m = lane & 31, h = lane >> 5;
  const int stripe = blockIdx.x, by = blockIdx.y;

  // ---- A panel into registers: rows stripe*128 + wr*64 .. +64, all K
  short8 areg[2][16];
  #pragma unroll
  for (int g = 0; g < 2; ++g)
    #pragma unroll
    for (int ks = 0; ks < 16; ++ks)
      areg[g][ks] = *(const short8*)(PA +
          ((size_t)((stripe * 4 + wr * 2 + g) * 16 + ks)) * 512 + lane * 8);
  asm volatile("s_waitcnt vmcnt(0)" ::: "memory");

  floatx16 acc[2][2];

  // stage chunk (jj2, c2) -> buffer bufsel. Wave wv stages ks-slice wv for 4 ct frags.
  auto issue = [&](int jj2, int c2, int bufsel) {
    const short* base = PB + ((size_t)((by * 64 + jj2 * 4) * 16) + c2 * 4 + wv) * 512 + lane * 8;
    char* dst = smem + bufsel * 16384 + wv * 1024;
    #pragma unroll
    for (int ct = 0; ct < 4; ++ct)
      async16(base + (size_t)ct * 8192, dst + ct * 4096);
  };
  auto compute = [&](int c, int bufsel) {
    char* base = smem + bufsel * 16384 + lane * 16;
    #pragma unroll
    for (int ksl = 0; ksl < 4; ++ksl) {
      short8 b0 = *(const short8*)(base + ((wc * 2 + 0) * 4 + ksl) * 1024);
      short8 b1 = *(const short8*)(base + ((wc * 2 + 1) * 4 + ksl) * 1024);
      int ks = c * 4 + ksl;  // compile-time under unroll
      acc[0][0] = __builtin_amdgcn_mfma_f32_32x32x16_bf16(areg[0][ks], b0, acc[0][0], 0, 0, 0);
      acc[1][0] = __builtin_amdgcn_mfma_f32_32x32x16_bf16(areg[1][ks], b0, acc[1][0], 0, 0, 0);
      acc[0][1] = __builtin_amdgcn_mfma_f32_32x32x16_bf16(areg[0][ks], b1, acc[0][1], 0, 0, 0);
      acc[1][1] = __builtin_amdgcn_mfma_f32_32x32x16_bf16(areg[1][ks], b1, acc[1][1], 0, 0, 0);
    }
  };

  issue(0, 0, 0);
  issue(0, 1, 1);

  float Mr = -3.0e38f, Sr = 0.f;  // row LSE state: row = stripe*128 + wr*64 + wc*32 + m

  for (int jj = 0; jj < 16; ++jj) {
    #pragma unroll
    for (int rt = 0; rt < 2; ++rt)
      #pragma unroll
      for (int ctl = 0; ctl < 2; ++ctl)
        #pragma unroll
        for (int r = 0; r < 16; ++r) acc[rt][ctl][r] = 0.f;

    #pragma unroll
    for (int c = 0; c < 4; ++c) {
      if (jj == 15 && c == 3) { asm volatile("s_waitcnt vmcnt(0)" ::: "memory"); }
      else                    { asm volatile("s_waitcnt vmcnt(4)" ::: "memory"); }
      __builtin_amdgcn_s_barrier();
      asm volatile("" ::: "memory");
      compute(c, c & 1);
      asm volatile("" ::: "memory");
      __builtin_amdgcn_s_barrier();
      asm volatile("" ::: "memory");
      int nc = c + 2;
      int jj2 = jj + (nc >> 2);
      if (jj2 < 16) issue(jj2, nc & 3, nc & 1);
    }

    // ---- stats. acc[rt][ctl][reg]: row(in tile) = wr*64+rt*32+(reg&3)+8*(reg>>2)+4*h
    //                                col(in tile) = wc*64+ctl*32+m
    float v = -3.0e38f;
    #pragma unroll
    for (int rt = 0; rt < 2; ++rt)
      #pragma unroll
      for (int ctl = 0; ctl < 2; ++ctl)
        #pragma unroll
        for (int r = 0; r < 16; ++r) v = fmaxf(v, acc[rt][ctl][r]);
    #pragma unroll
    for (int off = 1; off < 64; off <<= 1) v = fmaxf(v, __shfl_xor(v, off));
    float msub = v - 96.f;

    #pragma unroll
    for (int rt = 0; rt < 2; ++rt)
      #pragma unroll
      for (int ctl = 0; ctl < 2; ++ctl)
        #pragma unroll
        for (int r = 0; r < 16; ++r) acc[rt][ctl][r] = HEXP2(acc[rt][ctl][r] - msub);

    // col partials: sum over 64 rows of wave tile (reg-local + xor32)
    #pragma unroll
    for (int ctl = 0; ctl < 2; ++ctl) {
      float cp = 0.f;
      #pragma unroll
      for (int r = 0; r < 16; ++r) cp += acc[0][ctl][r] + acc[1][ctl][r];
      cp += __shfl_xor(cp, 32);
      if (h == 0) colbuf[wr * 128 + wc * 64 + ctl * 32 + m] = make_float2(msub, cp);
    }

    // row partials: ctl-add, pack 4 rows -> float4, rowbuf[(wr*64+slot)*76 + row]
    #pragma unroll
    for (int rt = 0; rt < 2; ++rt)
      #pragma unroll
      for (int rq = 0; rq < 4; ++rq) {
        float4 rp;
        rp.x = acc[rt][0][rq * 4 + 0] + acc[rt][1][rq * 4 + 0];
        rp.y = acc[rt][0][rq * 4 + 1] + acc[rt][1][rq * 4 + 1];
        rp.z = acc[rt][0][rq * 4 + 2] + acc[rt][1][rq * 4 + 2];
        rp.w = acc[rt][0][rq * 4 + 3] + acc[rt][1][rq * 4 + 3];
        *(float4*)&rowbuf[(wr * 64 + wc * 32 + m) * 76 + rt * 32 + rq * 8 + h * 4] = rp;
      }
    asm volatile("s_waitcnt lgkmcnt(0)" ::: "memory");
    __builtin_amdgcn_s_barrier();
    asm volatile("" ::: "memory");

    // phase2 rows: this wave owns rows wc*32+m of the wr pair; halves split slots
    {
      float s = 0.f;
      #pragma unroll
      for (int k = 0; k < 32; ++k)
        s += rowbuf[(wr * 64 + h * 32 + k) * 76 + wc * 32 + m];
      s += __shfl_xor(s, 32);
      if (s > 0.f) {
        if (msub > Mr) { Sr = Sr * HEXP2(Mr - msub) + s; Mr = msub; }
        else           { Sr += s * HEXP2(msub - Mr); }
      }
    }
    // phase2 cols: merge wr=0/1 partials -> pC
    if (tid < 128) {
      float2 c0 = colbuf[tid], c1 = colbuf[128 + tid];
      float M = -3.0e38f, L = 0.f;
      if (c0.y > 0.f) { M = c0.x; L = c0.y; }
      if (c1.y > 0.f) {
        if (c1.x > M) { L = L * HEXP2(M - c1.x) + c1.y; M = c1.x; }
        else          { L += c1.y * HEXP2(c1.x - M); }
      }
      pC[(size_t)stripe * N_ + by * 2048 + jj * 128 + tid] = make_float2(M, L);
    }
    asm volatile("s_waitcnt lgkmcnt(0)" ::: "memory");
    __builtin_amdgcn_s_barrier();
    asm volatile("" ::: "memory");
  }

  if (h == 0)
    pR[(size_t)by * N_ + stripe * 128 + wr * 64 + wc * 32 + m] = make_float2(Mr, Sr);
}

// ---------------- merge: rows (8 partials) + cols (128 partials) -> LSE -> loss ----------------
__global__ void merge_kernel(const float2* __restrict__ pR, const float2* __restrict__ pC,
                             const float* __restrict__ diag2, float* __restrict__ accv) {
  int idx = blockIdx.x * 256 + threadIdx.x;  // 0..2N-1
  float M = -3.0e38f, L = 0.f;
  int i;
  if (idx < N_) {
    i = idx;
    #pragma unroll
    for (int g = 0; g < 8; ++g) {
      float2 w = pR[(size_t)g * N_ + i];
      if (w.y > 0.f) {
        if (w.x > M) { L = L * exp2f(M - w.x) + w.y; M = w.x; }
        else         { L += w.y * exp2f(w.x - M); }
      }
    }
  } else {
    i = idx - N_;
    for (int s = 0; s < 128; ++s) {
      float2 w = pC[(size_t)s * N_ + i];
      if (w.y > 0.f) {
        if (w.x > M) { L = L * exp2f(M - w.x) + w.y; M = w.x; }
        else         { L += w.y * exp2f(w.x - M); }
      }
    }
  }
  float val = (M + log2f(fmaxf(L, 1e-45f))) - diag2[i];

  __shared__ float red[256];
  red[threadIdx.x] = val;
  __syncthreads();
  #pragma unroll
  for (int s = 128; s > 0; s >>= 1) {
    if (threadIdx.x < s) red[threadIdx.x] += red[threadIdx.x + s];
    __syncthreads();
  }
  if (threadIdx.x == 0) atomicAdd(accv, red[0]);
}

__global__ void finalize_kernel(const float* __restrict__ accv, float* __restrict__ out) {
  out[0] = accv[0] * (0.69314718055994531f / 32768.0f);  // ln2 / (2N)
}

// ---------------- launch ----------------
extern "C" void kernel_launch(void* const* d_in, const int* in_sizes, int n_in,
                              void* d_out, int out_size, void* d_ws, size_t ws_size,
                              hipStream_t stream) {
  const float* img = (const float*)d_in[0];
  const float* txt = (const float*)d_in[1];
  const float* ls  = (const float*)d_in[2];
  float* out = (float*)d_out;

  char* ws = (char*)d_ws;
  short* PA    = (short*)(ws);                 //  8 MB
  short* PB    = (short*)(ws + 8388608);       //  8 MB
  float* diag2 = (float*)(ws + 16777216);      //  64 KB
  float* accv  = (float*)(ws + 16842752);      //  256 B
  float2* pR   = (float2*)(ws + 16843008);     //  1 MB  (8 x N)
  float2* pC   = (float2*)(ws + 17891584);     //  16 MB (128 x N)

  hipLaunchKernelGGL(prep_pack, dim3(2048), dim3(256), 0, stream, img, txt, ls, PA, PB, accv);
  hipLaunchKernelGGL(diag_kernel, dim3(N_ / 4), dim3(256), 0, stream, img, txt, ls, diag2);
  hipLaunchKernelGGL(gemm_stats, dim3(128, 8), dim3(256), 0, stream, PA, PB, pR, pC);
  hipLaunchKernelGGL(merge_kernel, dim3(2 * N_ / 256), dim3(256), 0, stream, pR, pC, diag2, accv);
  hipLaunchKernelGGL(finalize_kernel, dim3(1), dim3(1), 0, stream, accv, out);
}